// Round 2
// baseline (169.714 us; speedup 1.0000x reference)
//
#include <hip/hip_runtime.h>
#include <hip/hip_bf16.h>
#include <cstdint>
#include <cstddef>

#define CIN   512
#define COUT  512
#define LLEN  2048
#define BATCH 8
#define KTAP  8
#define LPAD  (LLEN + 8)   // 8 zero halo rows at the front of each batch

typedef __bf16 bf16x8_t __attribute__((ext_vector_type(8)));
typedef float  f32x4_t  __attribute__((ext_vector_type(4)));
typedef unsigned short u16x8_t __attribute__((ext_vector_type(8)));

__device__ __forceinline__ unsigned short f2bf(float f) {
  __bf16 h = (__bf16)f;                       // RNE fptrunc
  return __builtin_bit_cast(unsigned short, h);
}

__device__ __forceinline__ void gl2lds16(unsigned short* lds, const unsigned short* g) {
  __builtin_amdgcn_global_load_lds(
      (const __attribute__((address_space(1))) unsigned int*)g,
      (__attribute__((address_space(3))) unsigned int*)lds,
      16, 0, 0);
}

// ---------------- fused pre-pass (UNCHANGED) ----------------
// blocks [0, 2048): x (B,CIN,L) fp32 -> xtp (B, 8+L, CIN) bf16 transpose+cast
//                   (l0==0 blocks also zero the 8-row halo)
// blocks [2048, 3072): W (COUT*K, CIN) fp32 -> bf16 Wb, 8 elems/thread
__global__ __launch_bounds__(256) void prepass_kernel(
    const float* __restrict__ x, unsigned short* __restrict__ xtp,
    const float4* __restrict__ W, u16x8_t* __restrict__ Wb) {
  const int bid = blockIdx.x;
  const int t   = threadIdx.x;

  if (bid >= 2048) {                   // ---- W convert ----
    int idx = (bid - 2048) * 256 + t;  // 262144 threads, 8 elems each
    float4 a = W[idx * 2], b = W[idx * 2 + 1];
    u16x8_t o;
    o[0] = f2bf(a.x); o[1] = f2bf(a.y); o[2] = f2bf(a.z); o[3] = f2bf(a.w);
    o[4] = f2bf(b.x); o[5] = f2bf(b.y); o[6] = f2bf(b.z); o[7] = f2bf(b.w);
    Wb[idx] = o;
    return;
  }

  // ---- x transpose: 64(c) x 64(l) tile ----
  __shared__ float tile[64][65];
  const int b  = bid >> 8;             // 0..7
  const int c0 = ((bid >> 5) & 7) * 64;
  const int l0 = (bid & 31) * 64;

  if ((bid & 31) == 0 && t < 64) {     // halo zero: rows 0..7, cols c0..c0+63
    unsigned short* hp = xtp + ((size_t)b * LPAD + (t >> 3)) * CIN + c0 + (t & 7) * 8;
    *(u16x8_t*)hp = (u16x8_t){0, 0, 0, 0, 0, 0, 0, 0};
  }

  {
    const int cr = t >> 2;             // 0..63
    const int lv = (t & 3) * 16;       // 0,16,32,48
    const float* src = x + ((size_t)b * CIN + c0 + cr) * LLEN + l0 + lv;
#pragma unroll
    for (int i = 0; i < 4; ++i) {
      float4 v = *(const float4*)(src + 4 * i);
      tile[cr][lv + 4 * i + 0] = v.x;
      tile[cr][lv + 4 * i + 1] = v.y;
      tile[cr][lv + 4 * i + 2] = v.z;
      tile[cr][lv + 4 * i + 3] = v.w;
    }
  }
  __syncthreads();
  {
    const int l    = t >> 2;           // 0..63
    const int cseg = (t & 3) * 16;     // 0,16,32,48
    unsigned short ov[16];
#pragma unroll
    for (int u = 0; u < 16; ++u) ov[u] = f2bf(tile[cseg + u][l]);
    unsigned short* dst = xtp + ((size_t)b * LPAD + 8 + l0 + l) * CIN + c0 + cseg;
    *(u16x8_t*)dst       = *(const u16x8_t*)&ov[0];
    *(u16x8_t*)(dst + 8) = *(const u16x8_t*)&ov[8];
  }
}

// ---------------- fused conv GEMM ----------------
// C[o][l] (256x128 per block) = sum_k sum_c W[k*COUT+o][c] * xT[l-k][c].
// CHANGE vs round 1: LDS-read-BW was the binding term (3.15 GB -> 46 us floor
// at 69 TB/s with 64x32 wave tiles). Wave tile -> 64x64 (acc[4][4], m97
// pattern): LDS bytes/FLOP drops 1.5x -> 2.1 GB (30 us), below the 33 us MFMA
// floor. Block 256(o) x 128(l), 8 waves as 4(o) x 2(l). Grid 16x2x8 = 256
// blocks = exactly 1/CU, zero tail. LDS 98 KB -> 1 block/CU (2 waves/SIMD --
// acceptable: round 1 showed 4 vs 2 waves/SIMD is only ~5%). Per-tap compute
// ~1240 cyc/SIMD fully covers staging latency, so the per-tap barrier's vmcnt
// drain stays ~free. Swizzle/staging/halo/setprio unchanged; accumulation
// order over (ct,k,h) identical -> same numerics.

__global__ __launch_bounds__(512) void conv_gemm_kernel(
    const unsigned short* __restrict__ Wb,   // (K*COUT, CIN) bf16
    const unsigned short* __restrict__ xtp,  // (B, LPAD, CIN) bf16
    const float* __restrict__ bias,          // (COUT)
    float* __restrict__ y)                   // (B, COUT, LLEN) fp32
{
  __shared__ __align__(16) unsigned short As[2][256 * 64];  // 2 x 32 KB
  __shared__ __align__(16) unsigned short Bs[2][136 * 64];  // 2 x 17 KB (halo)

  const int t    = threadIdx.x;
  const int lane = t & 63;
  const int wid  = t >> 6;           // 0..7
  const int wm   = wid & 3;          // o quarter (0..3)
  const int wn   = wid >> 2;         // l half (0..1)
  const int l0   = blockIdx.x * 128;
  const int o0   = blockIdx.y * 256;
  const int b    = blockIdx.z;

  const int quad = lane >> 4;
  const int lrow = lane & 15;

  f32x4_t acc[4][4];
#pragma unroll
  for (int i = 0; i < 4; ++i)
#pragma unroll
    for (int j = 0; j < 4; ++j)
      acc[i][j] = (f32x4_t){0.f, 0.f, 0.f, 0.f};

  // staging: rows of 64 bf16 = 8 chunks of 16 B; LDS slot s of row r holds
  // source chunk s ^ (r & 7) (swizzle applied on the SOURCE address).
  // 512 threads cover 64 rows (8 KB) per round.
  const int srow    = t >> 3;                       // 0..63 per round
  const int schunk  = (t & 7) ^ (srow & 7);         // swizzled source chunk
  const int lds_off = t * 8;                        // elements (t*16 bytes)

  const unsigned short* xb = xtp + (size_t)b * LPAD * CIN;

  auto stage_A = [&](int kk, int buf) {             // 256 rows = 4 rounds
    const unsigned short* asrc =
        Wb + (size_t)((kk & 7) * COUT + o0 + srow) * CIN + (kk >> 3) * 64 + schunk * 8;
#pragma unroll
    for (int rd = 0; rd < 4; ++rd)
      gl2lds16(&As[buf][0] + lds_off + rd * 4096, asrc + (size_t)rd * 64 * CIN);
  };
  auto stage_B = [&](int ct, int buf) {             // 128 rows = 2 rounds + halo
    const int c0 = ct * 64;
    const unsigned short* src = xb + (size_t)(l0 + srow) * CIN + c0 + schunk * 8;
#pragma unroll
    for (int rd = 0; rd < 2; ++rd)
      gl2lds16(&Bs[buf][0] + lds_off + rd * 4096, src + (size_t)rd * 64 * CIN);
    if (t < 64) {
      const int r2  = 128 + (t >> 3);               // halo rows 128..135
      const int ch2 = (t & 7) ^ (r2 & 7);
      gl2lds16(&Bs[buf][0] + 128 * 64 + t * 8,
               xb + (size_t)(l0 + r2) * CIN + c0 + ch2 * 8);
    }
  };

  stage_B(0, 0);
  stage_A(0, 0);
  __syncthreads();

#pragma unroll 1
  for (int kk = 0; kk < 64; ++kk) {
    const int k  = kk & 7;
    const int ct = kk >> 3;
    // issue next-phase staging FIRST (in flight across this tap's compute)
    if (kk + 1 < 64) stage_A(kk + 1, (kk + 1) & 1);
    if (k == 7 && ct + 1 < 8) stage_B(ct + 1, (ct + 1) & 1);

    const unsigned short* Ac = &As[kk & 1][0];
    const unsigned short* Bc = &Bs[ct & 1][0];
#pragma unroll
    for (int h = 0; h < 2; ++h) {
      bf16x8_t af[4], bfr[4];
#pragma unroll
      for (int i = 0; i < 4; ++i) {
        int row  = wm * 64 + i * 16 + lrow;
        int slot = (h * 4 + quad) ^ (row & 7);
        af[i] = *(const bf16x8_t*)(Ac + row * 64 + slot * 8);
      }
#pragma unroll
      for (int j = 0; j < 4; ++j) {
        int row  = (8 - k) + wn * 64 + j * 16 + lrow;   // halo shift
        int slot = (h * 4 + quad) ^ (row & 7);
        bfr[j] = *(const bf16x8_t*)(Bc + row * 64 + slot * 8);
      }
      __builtin_amdgcn_s_setprio(1);
#pragma unroll
      for (int i = 0; i < 4; ++i)
#pragma unroll
        for (int j = 0; j < 4; ++j)
          acc[i][j] = __builtin_amdgcn_mfma_f32_16x16x32_bf16(af[i], bfr[j], acc[i][j], 0, 0, 0);
      __builtin_amdgcn_s_setprio(0);
    }
    __syncthreads();  // single barrier: guards buffer swap; vmcnt drain ~free
  }

  // epilogue: D layout col = lane&15 (=l), row = quad*4+reg (=o)
#pragma unroll
  for (int i = 0; i < 4; ++i) {
    const int o_base = o0 + wm * 64 + i * 16 + quad * 4;
    const float4 bv = *(const float4*)(bias + o_base);
    const float bvr[4] = {bv.x, bv.y, bv.z, bv.w};
#pragma unroll
    for (int j = 0; j < 4; ++j) {
      const int l = l0 + wn * 64 + j * 16 + lrow;
#pragma unroll
      for (int r = 0; r < 4; ++r) {
        y[((size_t)b * COUT + o_base + r) * LLEN + l] = acc[i][j][r] + bvr[r];
      }
    }
  }
}

// ---------------- launch ----------------

extern "C" void kernel_launch(void* const* d_in, const int* in_sizes, int n_in,
                              void* d_out, int out_size, void* d_ws, size_t ws_size,
                              hipStream_t stream) {
  const float* x    = (const float*)d_in[0];   // (8, 512, 2048)
  const float* W    = (const float*)d_in[1];   // (4096, 512)
  const float* bias = (const float*)d_in[2];   // (512)
  float* y          = (float*)d_out;           // (8, 512, 2048)

  unsigned short* xtp = (unsigned short*)d_ws;                     // 16,842,752 B
  unsigned short* Wb  = (unsigned short*)((char*)d_ws +
                        (size_t)BATCH * LPAD * CIN * sizeof(unsigned short));

  prepass_kernel<<<2048 + 1024, 256, 0, stream>>>(
      x, xtp, (const float4*)W, (u16x8_t*)Wb);
  conv_gemm_kernel<<<dim3(LLEN / 128, COUT / 256, BATCH), 512, 0, stream>>>(
      Wb, xtp, bias, y);
}

// Round 3
// 147.827 us; speedup vs baseline: 1.1481x; 1.1481x over previous
//
#include <hip/hip_runtime.h>
#include <hip/hip_bf16.h>
#include <cstdint>
#include <cstddef>

#define CIN   512
#define COUT  512
#define LLEN  2048
#define BATCH 8
#define KTAP  8
#define LPAD  (LLEN + 8)   // 8 zero halo rows at the front of each batch

typedef __bf16 bf16x8_t __attribute__((ext_vector_type(8)));
typedef float  f32x4_t  __attribute__((ext_vector_type(4)));
typedef unsigned short u16x8_t __attribute__((ext_vector_type(8)));

__device__ __forceinline__ unsigned short f2bf(float f) {
  __bf16 h = (__bf16)f;                       // RNE fptrunc
  return __builtin_bit_cast(unsigned short, h);
}

__device__ __forceinline__ void gl2lds16(unsigned short* lds, const unsigned short* g) {
  __builtin_amdgcn_global_load_lds(
      (const __attribute__((address_space(1))) unsigned int*)g,
      (__attribute__((address_space(3))) unsigned int*)lds,
      16, 0, 0);
}

// ---------------- fused pre-pass (UNCHANGED) ----------------
// blocks [0, 2048): x (B,CIN,L) fp32 -> xtp (B, 8+L, CIN) bf16 transpose+cast
//                   (l0==0 blocks also zero the 8-row halo)
// blocks [2048, 3072): W (COUT*K, CIN) fp32 -> bf16 Wb, 8 elems/thread
__global__ __launch_bounds__(256) void prepass_kernel(
    const float* __restrict__ x, unsigned short* __restrict__ xtp,
    const float4* __restrict__ W, u16x8_t* __restrict__ Wb) {
  const int bid = blockIdx.x;
  const int t   = threadIdx.x;

  if (bid >= 2048) {                   // ---- W convert ----
    int idx = (bid - 2048) * 256 + t;  // 262144 threads, 8 elems each
    float4 a = W[idx * 2], b = W[idx * 2 + 1];
    u16x8_t o;
    o[0] = f2bf(a.x); o[1] = f2bf(a.y); o[2] = f2bf(a.z); o[3] = f2bf(a.w);
    o[4] = f2bf(b.x); o[5] = f2bf(b.y); o[6] = f2bf(b.z); o[7] = f2bf(b.w);
    Wb[idx] = o;
    return;
  }

  // ---- x transpose: 64(c) x 64(l) tile ----
  __shared__ float tile[64][65];
  const int b  = bid >> 8;             // 0..7
  const int c0 = ((bid >> 5) & 7) * 64;
  const int l0 = (bid & 31) * 64;

  if ((bid & 31) == 0 && t < 64) {     // halo zero: rows 0..7, cols c0..c0+63
    unsigned short* hp = xtp + ((size_t)b * LPAD + (t >> 3)) * CIN + c0 + (t & 7) * 8;
    *(u16x8_t*)hp = (u16x8_t){0, 0, 0, 0, 0, 0, 0, 0};
  }

  {
    const int cr = t >> 2;             // 0..63
    const int lv = (t & 3) * 16;       // 0,16,32,48
    const float* src = x + ((size_t)b * CIN + c0 + cr) * LLEN + l0 + lv;
#pragma unroll
    for (int i = 0; i < 4; ++i) {
      float4 v = *(const float4*)(src + 4 * i);
      tile[cr][lv + 4 * i + 0] = v.x;
      tile[cr][lv + 4 * i + 1] = v.y;
      tile[cr][lv + 4 * i + 2] = v.z;
      tile[cr][lv + 4 * i + 3] = v.w;
    }
  }
  __syncthreads();
  {
    const int l    = t >> 2;           // 0..63
    const int cseg = (t & 3) * 16;     // 0,16,32,48
    unsigned short ov[16];
#pragma unroll
    for (int u = 0; u < 16; ++u) ov[u] = f2bf(tile[cseg + u][l]);
    unsigned short* dst = xtp + ((size_t)b * LPAD + 8 + l0 + l) * CIN + c0 + cseg;
    *(u16x8_t*)dst       = *(const u16x8_t*)&ov[0];
    *(u16x8_t*)(dst + 8) = *(const u16x8_t*)&ov[8];
  }
}

// ---------------- fused conv GEMM ----------------
// C[o][l] (128x128 per block) = sum_k sum_c W[k*COUT+o][c] * xT[l-k][c].
// Round-3 structure: R1's shell (512 thr / 8 waves, 66 KB LDS -> 2 blk/CU,
// 4 waves/SIMD) but waves split 2(o) x 2(l) x 2(K-half): wave hg=wid>>2
// computes k-slots hg*4+quad only, on a full 64x64 tile. Per wave-tap LDS
// reads drop 12 KB -> 8 KB (total 3.15 -> 2.1 GB; R1 was at 92% of the LDS
// read ceiling). Epilogue reduces the hg pairs through LDS (reusing As/Bs
// space). Staging/swizzle/halo/single-barrier-per-tap identical to R1.

__global__ __launch_bounds__(512, 4) void conv_gemm_kernel(
    const unsigned short* __restrict__ Wb,   // (K*COUT, CIN) bf16
    const unsigned short* __restrict__ xtp,  // (B, LPAD, CIN) bf16
    const float* __restrict__ bias,          // (COUT)
    float* __restrict__ y)                   // (B, COUT, LLEN) fp32
{
  // As[2]: 2 x 128*64 bf16 = 32 KB at offset 0
  // Bs[2]: 2 x 136*64 bf16 = 34 KB at offset 32768
  // epilogue reduction scratch: 64 KB fp32, aliased over the whole buffer
  __shared__ __align__(16) unsigned char smem[67584];

  const int t    = threadIdx.x;
  const int lane = t & 63;
  const int wid  = t >> 6;            // 0..7
  const int wm   = wid & 1;           // o half
  const int wn   = (wid >> 1) & 1;    // l half
  const int hg   = wid >> 2;          // K-half (k-slots hg*4 .. hg*4+3)
  const int l0   = blockIdx.x * 128;
  const int o0   = blockIdx.y * 128;
  const int b    = blockIdx.z;

  const int quad = lane >> 4;
  const int lrow = lane & 15;

  unsigned short* AsBuf = (unsigned short*)smem;            // [buf * 8192]
  unsigned short* BsBuf = (unsigned short*)(smem + 32768);  // [buf * 8704]

  f32x4_t acc[4][4];
#pragma unroll
  for (int i = 0; i < 4; ++i)
#pragma unroll
    for (int j = 0; j < 4; ++j)
      acc[i][j] = (f32x4_t){0.f, 0.f, 0.f, 0.f};

  // staging: rows of 64 bf16 = 8 chunks of 16 B; LDS slot s of row r holds
  // source chunk s ^ (r & 7) (swizzle applied on the SOURCE address).
  // 512 threads cover 64 rows (8 KB) per round.
  const int srow    = t >> 3;                       // 0..63 per round
  const int schunk  = (t & 7) ^ (srow & 7);         // swizzled source chunk
  const int lds_off = t * 8;                        // elements (t*16 bytes)

  const unsigned short* xb = xtp + (size_t)b * LPAD * CIN;

  auto stage_A = [&](int kk, int buf) {             // 128 rows = 2 rounds
    const unsigned short* asrc =
        Wb + (size_t)((kk & 7) * COUT + o0 + srow) * CIN + (kk >> 3) * 64 + schunk * 8;
#pragma unroll
    for (int rd = 0; rd < 2; ++rd)
      gl2lds16(AsBuf + buf * 8192 + lds_off + rd * 4096, asrc + (size_t)rd * 64 * CIN);
  };
  auto stage_B = [&](int ct, int buf) {             // 128 rows = 2 rounds + halo
    const int c0 = ct * 64;
    const unsigned short* src = xb + (size_t)(l0 + srow) * CIN + c0 + schunk * 8;
#pragma unroll
    for (int rd = 0; rd < 2; ++rd)
      gl2lds16(BsBuf + buf * 8704 + lds_off + rd * 4096, src + (size_t)rd * 64 * CIN);
    if (t < 64) {
      const int r2  = 128 + (t >> 3);               // halo rows 128..135
      const int ch2 = (t & 7) ^ (r2 & 7);
      gl2lds16(BsBuf + buf * 8704 + 128 * 64 + t * 8,
               xb + (size_t)(l0 + r2) * CIN + c0 + ch2 * 8);
    }
  };

  stage_B(0, 0);
  stage_A(0, 0);
  __syncthreads();

#pragma unroll 1
  for (int kk = 0; kk < 64; ++kk) {
    const int k  = kk & 7;
    const int ct = kk >> 3;
    // issue next-phase staging FIRST (in flight across this tap's compute)
    if (kk + 1 < 64) stage_A(kk + 1, (kk + 1) & 1);
    if (k == 7 && ct + 1 < 8) stage_B(ct + 1, (ct + 1) & 1);

    const unsigned short* Ac = AsBuf + (kk & 1) * 8192;
    const unsigned short* Bc = BsBuf + (ct & 1) * 8704;
    bf16x8_t af[4], bfr[4];
#pragma unroll
    for (int i = 0; i < 4; ++i) {
      int row  = wm * 64 + i * 16 + lrow;
      int slot = (hg * 4 + quad) ^ (row & 7);
      af[i] = *(const bf16x8_t*)(Ac + row * 64 + slot * 8);
    }
#pragma unroll
    for (int j = 0; j < 4; ++j) {
      int row  = (8 - k) + wn * 64 + j * 16 + lrow;   // halo shift
      int slot = (hg * 4 + quad) ^ (row & 7);
      bfr[j] = *(const bf16x8_t*)(Bc + row * 64 + slot * 8);
    }
    __builtin_amdgcn_s_setprio(1);
#pragma unroll
    for (int i = 0; i < 4; ++i)
#pragma unroll
      for (int j = 0; j < 4; ++j)
        acc[i][j] = __builtin_amdgcn_mfma_f32_16x16x32_bf16(af[i], bfr[j], acc[i][j], 0, 0, 0);
    __builtin_amdgcn_s_setprio(0);
    __syncthreads();  // single barrier: guards buffer swap; vmcnt drain ~free
  }

  // ---- cross-hg reduction through LDS (reuse As/Bs space; 16 KB per pair) ----
  float* red = (float*)smem + (size_t)(wn * 2 + wm) * 4096;
  if (hg == 1) {
#pragma unroll
    for (int i = 0; i < 4; ++i)
#pragma unroll
      for (int j = 0; j < 4; ++j)
#pragma unroll
        for (int r = 0; r < 4; ++r)
          red[((i * 4 + j) * 4 + r) * 64 + lane] = acc[i][j][r];
  }
  __syncthreads();
  if (hg == 0) {
    // epilogue: D layout col = lane&15 (=l), row = quad*4+reg (=o)
#pragma unroll
    for (int i = 0; i < 4; ++i) {
      const int o_base = o0 + wm * 64 + i * 16 + quad * 4;
      const float4 bv = *(const float4*)(bias + o_base);
      const float bvr[4] = {bv.x, bv.y, bv.z, bv.w};
#pragma unroll
      for (int j = 0; j < 4; ++j) {
        const int l = l0 + wn * 64 + j * 16 + lrow;
#pragma unroll
        for (int r = 0; r < 4; ++r) {
          float v = acc[i][j][r] + red[((i * 4 + j) * 4 + r) * 64 + lane];
          y[((size_t)b * COUT + o_base + r) * LLEN + l] = v + bvr[r];
        }
      }
    }
  }
}

// ---------------- launch ----------------

extern "C" void kernel_launch(void* const* d_in, const int* in_sizes, int n_in,
                              void* d_out, int out_size, void* d_ws, size_t ws_size,
                              hipStream_t stream) {
  const float* x    = (const float*)d_in[0];   // (8, 512, 2048)
  const float* W    = (const float*)d_in[1];   // (4096, 512)
  const float* bias = (const float*)d_in[2];   // (512)
  float* y          = (float*)d_out;           // (8, 512, 2048)

  unsigned short* xtp = (unsigned short*)d_ws;                     // 16,842,752 B
  unsigned short* Wb  = (unsigned short*)((char*)d_ws +
                        (size_t)BATCH * LPAD * CIN * sizeof(unsigned short));

  prepass_kernel<<<2048 + 1024, 256, 0, stream>>>(
      x, xtp, (const float4*)W, (u16x8_t*)Wb);
  conv_gemm_kernel<<<dim3(LLEN / 128, COUT / 128, BATCH), 512, 0, stream>>>(
      Wb, xtp, bias, y);
}

// Round 4
// 144.813 us; speedup vs baseline: 1.1720x; 1.0208x over previous
//
#include <hip/hip_runtime.h>
#include <hip/hip_bf16.h>
#include <cstdint>
#include <cstddef>

#define CIN   512
#define COUT  512
#define LLEN  2048
#define BATCH 8
#define KTAP  8
#define LPAD  (LLEN + 8)   // 8 zero halo rows at the front of each batch

typedef __bf16 bf16x8_t __attribute__((ext_vector_type(8)));
typedef float  f32x4_t  __attribute__((ext_vector_type(4)));
typedef unsigned short u16x8_t __attribute__((ext_vector_type(8)));

__device__ __forceinline__ unsigned short f2bf(float f) {
  __bf16 h = (__bf16)f;                       // RNE fptrunc
  return __builtin_bit_cast(unsigned short, h);
}

__device__ __forceinline__ void gl2lds16(unsigned short* lds, const unsigned short* g) {
  __builtin_amdgcn_global_load_lds(
      (const __attribute__((address_space(1))) unsigned int*)g,
      (__attribute__((address_space(3))) unsigned int*)lds,
      16, 0, 0);
}

// ---------------- fused pre-pass ----------------
// blocks [0, 2048): x (B,CIN,L) fp32 -> xtp (B, 8+L, CIN) bf16 transpose+cast
// blocks [2048, 3072): W (COUT*K, CIN) fp32 -> Wf bf16 FRAGMENT-MAJOR:
//   off16B = k*32768 + o128*8192 + wm*4096 + hg*2048 + ct*256 + i*64 + lane
//   (lane = quad*16 + lrow; o = o128*128+wm*64+i*16+lrow; c = ct*64+(hg*4+quad)*8+e)
// so the conv kernel's af[i] load is base + lane*16B: perfectly coalesced.
__global__ __launch_bounds__(256) void prepass_kernel(
    const float* __restrict__ x, unsigned short* __restrict__ xtp,
    const float4* __restrict__ W, u16x8_t* __restrict__ Wf) {
  const int bid = blockIdx.x;
  const int t   = threadIdx.x;

  if (bid >= 2048) {                   // ---- W convert to fragment layout ----
    int idx = (bid - 2048) * 256 + t;  // 262144 chunks of 8 c-elems
    float4 a = W[idx * 2], b = W[idx * 2 + 1];
    u16x8_t o;
    o[0] = f2bf(a.x); o[1] = f2bf(a.y); o[2] = f2bf(a.z); o[3] = f2bf(a.w);
    o[4] = f2bf(b.x); o[5] = f2bf(b.y); o[6] = f2bf(b.z); o[7] = f2bf(b.w);
    const int row  = idx >> 6;         // k*COUT + o
    const int cch  = idx & 63;         // c chunk (8 elems)
    const int k    = row >> 9, oo = row & 511;
    const int o128 = oo >> 7, wm = (oo >> 6) & 1, fi = (oo >> 4) & 3, lrow = oo & 15;
    const int ct   = cch >> 3, chin = cch & 7, hg = chin >> 2, quad = chin & 3;
    const int lane = quad * 16 + lrow;
    const int off  = k * 32768 + o128 * 8192 + wm * 4096 + hg * 2048 +
                     ct * 256 + fi * 64 + lane;
    Wf[off] = o;
    return;
  }

  // ---- x transpose: 64(c) x 64(l) tile ----
  __shared__ float tile[64][65];
  const int b  = bid >> 8;             // 0..7
  const int c0 = ((bid >> 5) & 7) * 64;
  const int l0 = (bid & 31) * 64;

  if ((bid & 31) == 0 && t < 64) {     // halo zero: rows 0..7, cols c0..c0+63
    unsigned short* hp = xtp + ((size_t)b * LPAD + (t >> 3)) * CIN + c0 + (t & 7) * 8;
    *(u16x8_t*)hp = (u16x8_t){0, 0, 0, 0, 0, 0, 0, 0};
  }

  {
    const int cr = t >> 2;             // 0..63
    const int lv = (t & 3) * 16;       // 0,16,32,48
    const float* src = x + ((size_t)b * CIN + c0 + cr) * LLEN + l0 + lv;
#pragma unroll
    for (int i = 0; i < 4; ++i) {
      float4 v = *(const float4*)(src + 4 * i);
      tile[cr][lv + 4 * i + 0] = v.x;
      tile[cr][lv + 4 * i + 1] = v.y;
      tile[cr][lv + 4 * i + 2] = v.z;
      tile[cr][lv + 4 * i + 3] = v.w;
    }
  }
  __syncthreads();
  {
    const int l    = t >> 2;           // 0..63
    const int cseg = (t & 3) * 16;     // 0,16,32,48
    unsigned short ov[16];
#pragma unroll
    for (int u = 0; u < 16; ++u) ov[u] = f2bf(tile[cseg + u][l]);
    unsigned short* dst = xtp + ((size_t)b * LPAD + 8 + l0 + l) * CIN + c0 + cseg;
    *(u16x8_t*)dst       = *(const u16x8_t*)&ov[0];
    *(u16x8_t*)(dst + 8) = *(const u16x8_t*)&ov[8];
  }
}

// ---------------- fused conv GEMM ----------------
// C[o][l] (128x128 per block) = sum_k sum_c W[k*COUT+o][c] * xT[l-k][c].
// Round-4 structure: A (weights) now loaded DIRECTLY global->VGPR from the
// fragment-major Wf (coalesced 1 KB/instr, L1/L2-served, ~0.5 GB total) --
// the As LDS staging and its per-tap barrier are gone. Only B stays in LDS
// (k-dependent halo-shifted rows), double-buffered per ct chunk: barriers
// drop 64 -> 8, each drain waiting on a stage_B issued ~5000 cyc earlier
// (free). Waves 2(o) x 2(l) x 2(K-half) as in R3; epilogue reduces hg pairs
// through LDS. LDS 64 KB -> 2 blk/CU, 4 waves/SIMD.

__global__ __launch_bounds__(512, 4) void conv_gemm_kernel(
    const unsigned short* __restrict__ Wf,   // fragment-major bf16 (4 MB)
    const unsigned short* __restrict__ xtp,  // (B, LPAD, CIN) bf16
    const float* __restrict__ bias,          // (COUT)
    float* __restrict__ y)                   // (B, COUT, LLEN) fp32
{
  // Bs[2]: 2 x 136*64 bf16 = 34 KB; epilogue scratch 64 KB fp32 aliased.
  __shared__ __align__(16) unsigned char smem[65536];

  const int t    = threadIdx.x;
  const int lane = t & 63;
  const int wid  = t >> 6;            // 0..7
  const int wm   = wid & 1;           // o half
  const int wn   = (wid >> 1) & 1;    // l half
  const int hg   = wid >> 2;          // K-half (c-chunks hg*4 .. hg*4+3)
  const int l0   = blockIdx.x * 128;
  const int o0   = blockIdx.y * 128;
  const int b    = blockIdx.z;

  const int quad = lane >> 4;
  const int lrow = lane & 15;

  unsigned short* BsBuf = (unsigned short*)smem;   // [buf * 8704]

  f32x4_t acc[4][4];
#pragma unroll
  for (int i = 0; i < 4; ++i)
#pragma unroll
    for (int j = 0; j < 4; ++j)
      acc[i][j] = (f32x4_t){0.f, 0.f, 0.f, 0.f};

  // B staging: rows of 64 bf16 = 8 chunks of 16 B; LDS slot s of row r holds
  // source chunk s ^ (r & 7) (swizzle applied on the SOURCE address).
  const int srow    = t >> 3;                       // 0..63 per round
  const int schunk  = (t & 7) ^ (srow & 7);         // swizzled source chunk
  const int lds_off = t * 8;                        // elements (t*16 bytes)

  const unsigned short* xb = xtp + (size_t)b * LPAD * CIN;

  auto stage_B = [&](int ct, int buf) {             // 128 rows = 2 rounds + halo
    const int c0 = ct * 64;
    const unsigned short* src = xb + (size_t)(l0 + srow) * CIN + c0 + schunk * 8;
#pragma unroll
    for (int rd = 0; rd < 2; ++rd)
      gl2lds16(BsBuf + buf * 8704 + lds_off + rd * 4096, src + (size_t)rd * 64 * CIN);
    if (t < 64) {
      const int r2  = 128 + (t >> 3);               // halo rows 128..135
      const int ch2 = (t & 7) ^ (r2 & 7);
      gl2lds16(BsBuf + buf * 8704 + 128 * 64 + t * 8,
               xb + (size_t)(l0 + r2) * CIN + c0 + ch2 * 8);
    }
  };

  const u16x8_t* Wfp = (const u16x8_t*)Wf;
  // per-wave fragment base (16B units): o128*8192 + wm*4096 + hg*2048 + lane
  const int woff = blockIdx.y * 8192 + wm * 4096 + hg * 2048 + lane;

  stage_B(0, 0);
  __syncthreads();

#pragma unroll 1
  for (int ct = 0; ct < 8; ++ct) {
    if (ct + 1 < 8) stage_B(ct + 1, (ct + 1) & 1);  // in flight across 8 taps
    const unsigned short* Bc = BsBuf + (ct & 1) * 8704;
    const u16x8_t* wp = Wfp + woff + ct * 256;
#pragma unroll
    for (int k = 0; k < 8; ++k) {
      bf16x8_t af[4], bfr[4];
#pragma unroll
      for (int i = 0; i < 4; ++i)
        af[i] = __builtin_bit_cast(bf16x8_t, wp[k * 32768 + i * 64]);
#pragma unroll
      for (int j = 0; j < 4; ++j) {
        int row  = (8 - k) + wn * 64 + j * 16 + lrow;   // halo shift
        int slot = (hg * 4 + quad) ^ (row & 7);
        bfr[j] = *(const bf16x8_t*)(Bc + row * 64 + slot * 8);
      }
      __builtin_amdgcn_s_setprio(1);
#pragma unroll
      for (int i = 0; i < 4; ++i)
#pragma unroll
        for (int j = 0; j < 4; ++j)
          acc[i][j] = __builtin_amdgcn_mfma_f32_16x16x32_bf16(af[i], bfr[j], acc[i][j], 0, 0, 0);
      __builtin_amdgcn_s_setprio(0);
    }
    __syncthreads();  // one barrier per ct chunk (8 total)
  }

  // ---- cross-hg reduction through LDS (alias smem; 16 KB per (wm,wn) pair) ----
  float* red = (float*)smem + (size_t)(wn * 2 + wm) * 4096;
  if (hg == 1) {
#pragma unroll
    for (int i = 0; i < 4; ++i)
#pragma unroll
      for (int j = 0; j < 4; ++j)
#pragma unroll
        for (int r = 0; r < 4; ++r)
          red[((i * 4 + j) * 4 + r) * 64 + lane] = acc[i][j][r];
  }
  __syncthreads();
  if (hg == 0) {
    // epilogue: D layout col = lane&15 (=l), row = quad*4+reg (=o)
#pragma unroll
    for (int i = 0; i < 4; ++i) {
      const int o_base = o0 + wm * 64 + i * 16 + quad * 4;
      const float4 bv = *(const float4*)(bias + o_base);
      const float bvr[4] = {bv.x, bv.y, bv.z, bv.w};
#pragma unroll
      for (int j = 0; j < 4; ++j) {
        const int l = l0 + wn * 64 + j * 16 + lrow;
#pragma unroll
        for (int r = 0; r < 4; ++r) {
          float v = acc[i][j][r] + red[((i * 4 + j) * 4 + r) * 64 + lane];
          y[((size_t)b * COUT + o_base + r) * LLEN + l] = v + bvr[r];
        }
      }
    }
  }
}

// ---------------- launch ----------------

extern "C" void kernel_launch(void* const* d_in, const int* in_sizes, int n_in,
                              void* d_out, int out_size, void* d_ws, size_t ws_size,
                              hipStream_t stream) {
  const float* x    = (const float*)d_in[0];   // (8, 512, 2048)
  const float* W    = (const float*)d_in[1];   // (4096, 512)
  const float* bias = (const float*)d_in[2];   // (512)
  float* y          = (float*)d_out;           // (8, 512, 2048)

  unsigned short* xtp = (unsigned short*)d_ws;                     // 16,842,752 B
  unsigned short* Wf  = (unsigned short*)((char*)d_ws +
                        (size_t)BATCH * LPAD * CIN * sizeof(unsigned short));

  prepass_kernel<<<2048 + 1024, 256, 0, stream>>>(
      x, xtp, (const float4*)W, (u16x8_t*)Wf);
  conv_gemm_kernel<<<dim3(LLEN / 128, COUT / 128, BATCH), 512, 0, stream>>>(
      Wf, xtp, bias, y);
}